// Round 2
// baseline (1974.420 us; speedup 1.0000x reference)
//
#include <hip/hip_runtime.h>
#include <hip/hip_bf16.h>

typedef unsigned int u32;
typedef unsigned short u16;
typedef _Float16 f16;
typedef float f32x2 __attribute__((ext_vector_type(2)));
typedef _Float16 f16x2 __attribute__((ext_vector_type(2)));

#define LN_EPS 1e-5f
#define T_STEPS 30
#define NAG 4096

__device__ __forceinline__ float bf2f(u16 v){
    union { u32 u; float f; } c; c.u = ((u32)v) << 16; return c.f;
}
__device__ __forceinline__ u16 f2bf(float f){
    union { float f; u32 u; } c; c.f = f;
    return (u16)((c.u + 0x7FFFu + ((c.u >> 16) & 1u)) >> 16);
}
// unpack two f16 to two f32
__device__ __forceinline__ f32x2 unpk_h2(u32 p){
    f16x2 h = __builtin_bit_cast(f16x2, p);
    f32x2 r; r[0] = (float)h[0]; r[1] = (float)h[1]; return r;
}
__device__ __forceinline__ u32 pk_h2(float a, float b){
    f16x2 h; h[0] = (f16)a; h[1] = (f16)b;
    return __builtin_bit_cast(u32, h);
}
// dtype probe: fp32 buffers read as u16 have random mantissa halves at even
// positions (~50% decode to |x|>=128); bf16 weight buffers (|w| < 1) never do.
__device__ __forceinline__ int detect_f32(const void* probe){
    const u16* p = (const u16*)probe;
    int bad = 0;
    #pragma unroll
    for (int i = 0; i < 32; i++){
        u32 e = (p[2*i] >> 7) & 0xFF;
        bad += (e >= 0x86) ? 1 : 0;
    }
    return bad > 4;
}
// uniform-branch external load (no speculative OOB reads)
__device__ __forceinline__ float ldin(const void* p, int i, int F){
    float v;
    if (F) v = ((const float*)p)[i];
    else   v = bf2f(((const u16*)p)[i]);
    return v;
}
__device__ __forceinline__ void wred64(float& s, float& q){
    #pragma unroll
    for (int m = 1; m < 64; m <<= 1){ s += __shfl_xor(s, m); q += __shfl_xor(q, m); }
}
__device__ __forceinline__ void wred32(float& s, float& q){
    #pragma unroll
    for (int m = 1; m < 32; m <<= 1){ s += __shfl_xor(s, m); q += __shfl_xor(q, m); }
}
__device__ __forceinline__ float lrelu(float x){ return fmaxf(x, 0.1f * x); }
__device__ __forceinline__ float sigm(float x){ return 1.0f / (1.0f + __expf(-x)); }
__device__ __forceinline__ float ftanh(float x){ return 1.0f - 2.0f / (1.0f + __expf(2.0f * x)); }
// LN over 128 values spread as 2 per lane across a 64-lane wave
__device__ __forceinline__ void ln128(float a0, float a1, float& o0, float& o1){
    float s = a0 + a1, q = a0*a0 + a1*a1;
    wred64(s, q);
    float m = s * (1.f/128.f), v = q * (1.f/128.f) - m*m;
    float rs = rsqrtf(fmaxf(v, 0.f) + LN_EPS);
    o0 = (a0 - m) * rs; o1 = (a1 - m) * rs;
}

// ---------------- K1: cond embeddings (both dirs): [N,2] -> 64 -> 128 ----------------
__global__ __launch_bounds__(64) void k_cond(
    const void* __restrict__ cond,
    const void* __restrict__ w1a, const void* __restrict__ b1a,
    const void* __restrict__ w2a, const void* __restrict__ b2a,
    const void* __restrict__ w1b, const void* __restrict__ b1b,
    const void* __restrict__ w2b, const void* __restrict__ b2b,
    const void* __restrict__ probe,
    f16* __restrict__ disp)
{
    __shared__ float x1s[64];
    int F = detect_f32(probe);
    int n = blockIdx.x, dir = blockIdx.y, lane = threadIdx.x;
    const void* w1 = dir ? w1b : w1a; const void* b1 = dir ? b1b : b1a;
    const void* w2 = dir ? w2b : w2a; const void* b2 = dir ? b2b : b2a;
    float c0 = ldin(cond, n*2, F), c1 = ldin(cond, n*2+1, F);
    float y = ldin(w1, lane*2, F) * c0 + ldin(w1, lane*2+1, F) * c1 + ldin(b1, lane, F);
    float s = y, q = y*y; wred64(s, q);
    float m = s * (1.f/64.f), v = q * (1.f/64.f) - m*m;
    float rs = rsqrtf(fmaxf(v, 0.f) + LN_EPS);
    x1s[lane] = lrelu((y - m) * rs);
    __syncthreads();
    float y0 = ldin(b2, lane, F), y1 = ldin(b2, lane+64, F);
    for (int k = 0; k < 64; k++){
        float xv = x1s[k];
        y0 += ldin(w2, lane*64+k, F) * xv;
        y1 += ldin(w2, (lane+64)*64+k, F) * xv;
    }
    float o0, o1; ln128(y0, y1, o0, o1);
    f16* dp = disp + ((size_t)dir * NAG + n) * 128;
    dp[lane] = (f16)lrelu(o0);
    dp[lane+64] = (f16)lrelu(o1);
}

// ---------------- K2: scene embedding: z[T,N,128] -> 32 -> 64, store f16 ----------------
__global__ __launch_bounds__(256) void k_emb(
    const void* __restrict__ z,
    const void* __restrict__ iw1, const void* __restrict__ ib1,
    const void* __restrict__ iw2, const void* __restrict__ ib2,
    const void* __restrict__ probe,
    f16* __restrict__ semb)
{
    __shared__ float w1T[128*32];   // [k][e]
    __shared__ float w2T[32*64];    // [k][e]
    __shared__ float zrow[4][128];
    __shared__ float x1s[4][32];
    int F = detect_f32(probe);
    int tid = threadIdx.x;
    for (int i = tid; i < 4096; i += 256){ int e = i >> 7, k = i & 127; w1T[k*32+e] = ldin(iw1, i, F); }
    for (int i = tid; i < 2048; i += 256){ int e = i >> 5, k = i & 31; w2T[k*64+e] = ldin(iw2, i, F); }
    __syncthreads();
    int w = tid >> 6, lane = tid & 63;
    float b1 = (lane < 32) ? ldin(ib1, lane & 31, F) : 0.f;
    float b2 = ldin(ib2, lane, F);
    for (int rr = 0; rr < 8; rr++){
        int row = (blockIdx.x * 4 + w) * 8 + rr;   // < 122880
        zrow[w][lane]    = ldin(z, row*128 + lane, F);
        zrow[w][lane+64] = ldin(z, row*128 + 64 + lane, F);
        __syncthreads();
        float y1 = b1;
        if (lane < 32){
            for (int k = 0; k < 128; k++) y1 += zrow[w][k] * w1T[k*32+lane];
        }
        float s = (lane<32)? y1 : 0.f, q = (lane<32)? y1*y1 : 0.f;
        wred32(s, q);
        float m = s*(1.f/32.f), v = q*(1.f/32.f)-m*m, rs = rsqrtf(fmaxf(v,0.f)+LN_EPS);
        if (lane < 32) x1s[w][lane] = lrelu((y1-m)*rs);
        __syncthreads();
        float y2 = b2;
        for (int k = 0; k < 32; k++) y2 += x1s[w][k] * w2T[k*64+lane];
        s = y2; q = y2*y2; wred64(s, q);
        m = s*(1.f/64.f); v = q*(1.f/64.f)-m*m; rs = rsqrtf(fmaxf(v,0.f)+LN_EPS);
        semb[(size_t)row*64+lane] = (f16)lrelu((y2-m)*rs);
    }
}

// ---------------- K4: fused bidirectional LN-GRU ----------------
// grid (128, 2): block owns 32 agents (8 waves x 4 agents) for all 30 steps of one direction.
// Whh/Wih stay in LDS as packed f16 pairs; h state in registers + f16-packed LDS copy for dots.
__global__ __launch_bounds__(512, 2) void k_gru(
    const f16* __restrict__ semb, const f16* __restrict__ disp,
    const void* __restrict__ wihA, const void* __restrict__ whhA,
    const void* __restrict__ bihA, const void* __restrict__ bhhA,
    const void* __restrict__ wihB, const void* __restrict__ whhB,
    const void* __restrict__ bihB, const void* __restrict__ bhhB,
    const void* __restrict__ probe,
    f16* __restrict__ hencF, f16* __restrict__ hencB)
{
    __shared__ u32 WhhT[64*384];   // [k][u] = (Whh[u][2k], Whh[u][2k+1]) f16 pair
    __shared__ u32 WihT[32*384];   // [k][u] = (Wih[u][2k], Wih[u][2k+1])
    __shared__ float brz[256];     // bih[u]+bhh[u] for u<256 (r,z gates)
    __shared__ float bin[128];     // bih[256+u]
    __shared__ float bhn[128];     // bhh[256+u]
    __shared__ u32 hbuf[32][64];   // f16 pairs of h per agent
    __shared__ u32 xbuf[32][32];   // f16 pairs of x per agent
    int F = detect_f32(probe);
    int tid = threadIdx.x, dir = blockIdx.y;
    const void* wih = dir ? wihB : wihA;  const void* whh = dir ? whhB : whhA;
    const void* bih = dir ? bihB : bihA;  const void* bhh = dir ? bhhB : bhhA;
    f16* henc = dir ? hencB : hencF;
    for (int i = tid; i < 24576; i += 512){
        int u = i >> 6, k = i & 63;
        WhhT[k*384 + u] = pk_h2(ldin(whh, 2*i, F), ldin(whh, 2*i+1, F));
    }
    for (int i = tid; i < 12288; i += 512){
        int u = i >> 5, k = i & 31;
        WihT[k*384 + u] = pk_h2(ldin(wih, 2*i, F), ldin(wih, 2*i+1, F));
    }
    if (tid < 256) brz[tid] = ldin(bih, tid, F) + ldin(bhh, tid, F);
    else if (tid < 384){ bin[tid-256] = ldin(bih, tid, F); bhn[tid-256] = ldin(bhh, tid, F); }
    __syncthreads();
    int w = tid >> 6, lane = tid & 63;
    int nb = blockIdx.x * 32 + w * 4;   // first agent of this wave
    float hreg[4][2];
    #pragma unroll
    for (int a = 0; a < 4; a++){
        const f16* dp = disp + ((size_t)dir*NAG + nb + a)*128;
        hreg[a][0] = (float)dp[lane]; hreg[a][1] = (float)dp[lane+64];
        int s0 = (2*lane) & 63, s1 = (2*lane+1) & 63;
        float e0 = __shfl(hreg[a][0], s0), o0 = __shfl(hreg[a][1], s0);
        float e1 = __shfl(hreg[a][0], s1), o1 = __shfl(hreg[a][1], s1);
        hbuf[w*4+a][lane] = pk_h2((lane<32)?e0:o0, (lane<32)?e1:o1);
    }
    const u32* semb32 = (const u32*)semb;
    for (int t = 0; t < T_STEPS; t++){
        int tx = dir ? (T_STEPS-1-t) : t;
        #pragma unroll
        for (int a = 0; a < 4; a++){
            if (lane < 32) xbuf[w*4+a][lane] = semb32[((size_t)tx*NAG + nb + a)*32 + lane];
        }
        __syncthreads();   // hbuf (prev step) + xbuf (this step) visible
        f32x2 ar[4][2], az[4][2], ai[4][2], ah[4][2];
        #pragma unroll
        for (int a = 0; a < 4; a++){
            #pragma unroll
            for (int s2 = 0; s2 < 2; s2++){
                int u = s2*64 + lane;
                ar[a][s2][0] = brz[u];      ar[a][s2][1] = 0.f;
                az[a][s2][0] = brz[128+u];  az[a][s2][1] = 0.f;
                ai[a][s2][0] = bin[u];      ai[a][s2][1] = 0.f;
                ah[a][s2][0] = bhn[u];      ah[a][s2][1] = 0.f;
            }
        }
        // hh dots: unit u = s2*64+lane; even/odd k partials in f32x2 lanes
        #pragma unroll 2
        for (int k = 0; k < 64; k++){
            const u32* wrow = &WhhT[k*384 + lane];
            f32x2 wr0 = unpk_h2(wrow[0]);
            f32x2 wr1 = unpk_h2(wrow[64]);
            f32x2 wz0 = unpk_h2(wrow[128]);
            f32x2 wz1 = unpk_h2(wrow[192]);
            f32x2 wn0 = unpk_h2(wrow[256]);
            f32x2 wn1 = unpk_h2(wrow[320]);
            #pragma unroll
            for (int a = 0; a < 4; a++){
                f32x2 hh = unpk_h2(hbuf[w*4+a][k]);
                ar[a][0] += hh*wr0; ar[a][1] += hh*wr1;
                az[a][0] += hh*wz0; az[a][1] += hh*wz1;
                ah[a][0] += hh*wn0; ah[a][1] += hh*wn1;
            }
        }
        // ih dots (fused xg)
        #pragma unroll 2
        for (int k = 0; k < 32; k++){
            const u32* wrow = &WihT[k*384 + lane];
            f32x2 wr0 = unpk_h2(wrow[0]);
            f32x2 wr1 = unpk_h2(wrow[64]);
            f32x2 wz0 = unpk_h2(wrow[128]);
            f32x2 wz1 = unpk_h2(wrow[192]);
            f32x2 wn0 = unpk_h2(wrow[256]);
            f32x2 wn1 = unpk_h2(wrow[320]);
            #pragma unroll
            for (int a = 0; a < 4; a++){
                f32x2 xx = unpk_h2(xbuf[w*4+a][k]);
                ar[a][0] += xx*wr0; ar[a][1] += xx*wr1;
                az[a][0] += xx*wz0; az[a][1] += xx*wz1;
                ai[a][0] += xx*wn0; ai[a][1] += xx*wn1;
            }
        }
        #pragma unroll
        for (int a = 0; a < 4; a++){
            float arr0 = ar[a][0][0]+ar[a][0][1], arr1 = ar[a][1][0]+ar[a][1][1];
            float azz0 = az[a][0][0]+az[a][0][1], azz1 = az[a][1][0]+az[a][1][1];
            float aii0 = ai[a][0][0]+ai[a][0][1], aii1 = ai[a][1][0]+ai[a][1][1];
            float ahh0 = ah[a][0][0]+ah[a][0][1], ahh1 = ah[a][1][0]+ah[a][1][1];
            float g0, g1;
            ln128(arr0, arr1, g0, g1);
            float r0 = sigm(g0), r1 = sigm(g1);
            ln128(azz0, azz1, g0, g1);
            float z0 = sigm(g0), z1 = sigm(g1);
            float p0 = aii0 + r0*ahh0, p1 = aii1 + r1*ahh1;
            ln128(p0, p1, g0, g1);
            float n0 = ftanh(g0), n1 = ftanh(g1);
            float hn0 = (1.f-z0)*n0 + z0*hreg[a][0];
            float hn1 = (1.f-z1)*n1 + z1*hreg[a][1];
            hreg[a][0] = hn0; hreg[a][1] = hn1;
            f16* hp = henc + ((size_t)tx*NAG + nb + a)*128;
            hp[lane] = (f16)hn0; hp[lane+64] = (f16)hn1;
            int sl0 = (2*lane) & 63, sl1 = (2*lane+1) & 63;
            float e0 = __shfl(hn0, sl0), o0 = __shfl(hn1, sl0);
            float e1 = __shfl(hn0, sl1), o1 = __shfl(hn1, sl1);
            hbuf[w*4+a][lane] = pk_h2((lane<32)?e0:o0, (lane<32)?e1:o1);
        }
    }
}

// ---------------- K5: seq = block((hf+hb)*0.5, sw) ----------------
__global__ __launch_bounds__(256) void k_seq(
    const f16* __restrict__ hf, const f16* __restrict__ hb,
    const void* __restrict__ sw, const void* __restrict__ sb,
    const void* __restrict__ probe,
    f16* __restrict__ seqo)
{
    __shared__ float wT[128*64];   // [k][e]
    __shared__ float inr[4][128];
    int F = detect_f32(probe);
    int tid = threadIdx.x;
    for (int i = tid; i < 8192; i += 256){ int e = i >> 7, k = i & 127; wT[k*64+e] = ldin(sw, i, F); }
    __syncthreads();
    int w = tid >> 6, lane = tid & 63;
    float b = ldin(sb, lane, F);
    for (int rr = 0; rr < 8; rr++){
        int row = (blockIdx.x*4 + w)*8 + rr;
        const f16* pf = hf + (size_t)row*128;
        const f16* pb = hb + (size_t)row*128;
        inr[w][lane]    = 0.5f*((float)pf[lane] + (float)pb[lane]);
        inr[w][lane+64] = 0.5f*((float)pf[lane+64] + (float)pb[lane+64]);
        __syncthreads();
        float y = b;
        for (int k = 0; k < 128; k++) y += inr[w][k] * wT[k*64+lane];
        float s = y, q = y*y; wred64(s, q);
        float m = s*(1.f/64.f), v = q*(1.f/64.f)-m*m, rs = rsqrtf(fmaxf(v,0.f)+LN_EPS);
        seqo[(size_t)row*64+lane] = (f16)lrelu((y-m)*rs);
    }
}

// ---------------- K6: pairwise relative enc + mean over 7 partners ----------------
__global__ __launch_bounds__(256) void k_pair(
    const f16* __restrict__ seqi,
    const void* __restrict__ mw, const void* __restrict__ mb,
    const void* __restrict__ probe,
    f16* __restrict__ ave)
{
    __shared__ float wT[64*64];      // [k][e]
    __shared__ float srow[4][8][64]; // per-wave scene rows (read-only after stage)
    int F = detect_f32(probe);
    int tid = threadIdx.x;
    for (int i = tid; i < 4096; i += 256){ int e = i >> 6, k = i & 63; wT[k*64+e] = ldin(mw, i, F); }
    __syncthreads();
    int w = tid >> 6, lane = tid & 63;
    float b = ldin(mb, lane, F);
    int unit = blockIdx.x*4 + w;       // t*512 + scene, < 15360
    int t = unit >> 9, sc = unit & 511;
    int base = sc * 8;
    for (int i = 0; i < 8; i++)
        srow[w][i][lane] = (float)seqi[((size_t)t*NAG + base + i)*64 + lane];
    __syncthreads();
    for (int i = 0; i < 8; i++){
        float acc = 0.f;
        for (int j = 0; j < 8; j++){
            if (j == i) continue;
            float y = b;
            for (int k = 0; k < 64; k++)
                y += (srow[w][i][k] - srow[w][j][k]) * wT[k*64+lane];
            float s = y, q = y*y; wred64(s, q);
            float m = s*(1.f/64.f), v = q*(1.f/64.f)-m*m, rs = rsqrtf(fmaxf(v,0.f)+LN_EPS);
            acc += lrelu((y-m)*rs);
        }
        ave[((size_t)t*NAG + base + i)*64 + lane] = (f16)(acc * (1.f/7.f));
    }
}

// ---------------- K7: output head: concat -> 32 -> 2, tanh, transpose to [N,2,T] ----------------
__global__ __launch_bounds__(256) void k_out(
    const f16* __restrict__ seqi, const f16* __restrict__ ave,
    const void* __restrict__ ow1, const void* __restrict__ ob1,
    const void* __restrict__ ow2, const void* __restrict__ ob2,
    const void* __restrict__ probe,
    void* __restrict__ outp)
{
    __shared__ float w1T[128*32];   // [k][e]
    __shared__ float fullr[4][128];
    int F = detect_f32(probe);
    int tid = threadIdx.x;
    for (int i = tid; i < 4096; i += 256){ int e = i >> 7, k = i & 127; w1T[k*32+e] = ldin(ow1, i, F); }
    __syncthreads();
    int w = tid >> 6, lane = tid & 63;
    float b1  = (lane < 32) ? ldin(ob1, lane & 31, F) : 0.f;
    float o20 = (lane < 32) ? ldin(ow2, lane & 31, F) : 0.f;
    float o21 = (lane < 32) ? ldin(ow2, 32 + (lane & 31), F) : 0.f;
    float bo0 = ldin(ob2, 0, F), bo1 = ldin(ob2, 1, F);
    for (int rr = 0; rr < 8; rr++){
        int row = (blockIdx.x*4 + w)*8 + rr;
        fullr[w][lane]    = (float)seqi[(size_t)row*64+lane];
        fullr[w][64+lane] = (float)ave[(size_t)row*64+lane];
        __syncthreads();
        float y = b1;
        if (lane < 32){
            for (int k = 0; k < 128; k++) y += fullr[w][k]*w1T[k*32+lane];
        }
        float s = (lane<32)? y:0.f, q = (lane<32)? y*y:0.f; wred32(s, q);
        float m = s*(1.f/32.f), v = q*(1.f/32.f)-m*m, rs = rsqrtf(fmaxf(v,0.f)+LN_EPS);
        float h = lrelu((y-m)*rs);
        float p0 = (lane<32)? h*o20 : 0.f;
        float p1 = (lane<32)? h*o21 : 0.f;
        #pragma unroll
        for (int mm = 1; mm < 32; mm <<= 1){ p0 += __shfl_xor(p0, mm); p1 += __shfl_xor(p1, mm); }
        if (lane == 0){
            int tt = row >> 12, n = row & 4095;
            float v0 = ftanh(p0 + bo0), v1 = ftanh(p1 + bo1);
            size_t i0 = (size_t)(n*2)*30 + tt, i1 = (size_t)(n*2+1)*30 + tt;
            if (F){
                ((float*)outp)[i0] = v0; ((float*)outp)[i1] = v1;
            } else {
                ((u16*)outp)[i0] = f2bf(v0); ((u16*)outp)[i1] = f2bf(v1);
            }
        }
    }
}

extern "C" void kernel_launch(void* const* d_in, const int* in_sizes, int n_in,
                              void* d_out, int out_size, void* d_ws, size_t ws_size,
                              hipStream_t stream)
{
    const void* cond = d_in[0];
    const void* z    = d_in[1];
    const void* cw1  = d_in[2];
    const void* cb1  = d_in[3];
    const void* cw2  = d_in[4];
    const void* cb2  = d_in[5];
    const void* cbw1 = d_in[6];
    const void* cbb1 = d_in[7];
    const void* cbw2 = d_in[8];
    const void* cbb2 = d_in[9];
    const void* iw1  = d_in[10];
    const void* ib1  = d_in[11];
    const void* iw2  = d_in[12];
    const void* ib2  = d_in[13];
    const void* wih  = d_in[14];
    const void* whh  = d_in[15];
    const void* bih  = d_in[16];
    const void* bhh  = d_in[17];
    const void* wihb = d_in[18];
    const void* whhb = d_in[19];
    const void* bihb = d_in[20];
    const void* bhhb = d_in[21];
    const void* sw   = d_in[22];
    const void* sb   = d_in[23];
    const void* mw   = d_in[24];
    const void* mb   = d_in[25];
    const void* ow1  = d_in[26];
    const void* ob1  = d_in[27];
    const void* ow2  = d_in[28];
    const void* ob2  = d_in[29];
    const void* probe = whh;   // dtype-detection probe buffer

    char* ws = (char*)d_ws;
    size_t off = 0;
    f16* disp  = (f16*)(ws + off); off += (size_t)2*NAG*128*2;          //  2,097,152
    f16* semb  = (f16*)(ws + off); off += (size_t)T_STEPS*NAG*64*2;     // 15,728,640
    f16* hencF = (f16*)(ws + off); off += (size_t)T_STEPS*NAG*128*2;    // 31,457,280
    f16* hencB = (f16*)(ws + off); off += (size_t)T_STEPS*NAG*128*2;    // 31,457,280
    f16* seqb  = (f16*)(ws + off); off += (size_t)T_STEPS*NAG*64*2;     // 15,728,640
    f16* aveb  = (f16*)(ws + off); off += (size_t)T_STEPS*NAG*64*2;     // 15,728,640

    k_cond<<<dim3(4096,2), 64, 0, stream>>>(cond, cw1,cb1,cw2,cb2, cbw1,cbb1,cbw2,cbb2, probe, disp);
    k_emb<<<3840, 256, 0, stream>>>(z, iw1,ib1,iw2,ib2, probe, semb);
    k_gru<<<dim3(128,2), 512, 0, stream>>>(semb, disp, wih,whh,bih,bhh, wihb,whhb,bihb,bhhb, probe, hencF, hencB);
    k_seq<<<3840, 256, 0, stream>>>(hencF, hencB, sw, sb, probe, seqb);
    k_pair<<<3840, 256, 0, stream>>>(seqb, mw, mb, probe, aveb);
    k_out<<<3840, 256, 0, stream>>>(seqb, aveb, ow1,ob1,ow2,ob2, probe, d_out);
}